// Round 1
// baseline (4053.139 us; speedup 1.0000x reference)
//
#include <hip/hip_runtime.h>
#include <hip/hip_bf16.h>
#include <cmath>

// Problem: N=64, T=512, D=512, H=512
//   xw = x @ Wx + b            (N*T, D) @ (D, H)   -- parallel GEMM
//   h_t = tanh(xw_t + h_{t-1} @ Wh)                -- sequential over T
// out[n][t][:] = h_t[n][:]  (fp32)
//
// Kernel A writes xw into d_out; kernel B consumes out[n][t][:] at step t and
// overwrites it with h_t (read-before-write within the step, same wg only).

#define MTOT 32768   // N*T
#define DH   512

// ---------------- Kernel A: xw = x @ Wx + b  (fp32 LDS-tiled GEMM) ----------
// BM=64, BN=64, BK=16; 256 threads; each thread computes a 4x4 micro-tile.
__global__ __launch_bounds__(256) void xw_gemm(
    const float* __restrict__ X,    // (32768, 512)
    const float* __restrict__ Wx,   // (512, 512)
    const float* __restrict__ b,    // (512,)
    float* __restrict__ XW)         // (32768, 512) == d_out
{
    __shared__ float As[16][64];   // [k][m]
    __shared__ float Bs[16][64];   // [k][j]

    const int bm = blockIdx.x * 64;
    const int bn = blockIdx.y * 64;
    const int tid = threadIdx.x;
    const int tr = tid >> 4;       // 0..15
    const int tc = tid & 15;       // 0..15

    float acc[4][4] = {};

    for (int k0 = 0; k0 < DH; k0 += 16) {
        // Load A tile: rows bm..bm+63, k columns k0..k0+15 -> As[k][m]
        {
            int m  = tid >> 2;            // 0..63
            int kk = (tid & 3) * 4;       // 0,4,8,12
            const float4 v = *(const float4*)&X[(size_t)(bm + m) * DH + k0 + kk];
            As[kk + 0][m] = v.x; As[kk + 1][m] = v.y;
            As[kk + 2][m] = v.z; As[kk + 3][m] = v.w;
        }
        // Load B tile: Wx rows k0..k0+15, cols bn..bn+63 -> Bs[k][j]
        {
            int k  = tid >> 4;            // 0..15
            int j4 = (tid & 15) * 4;      // 0..60
            *(float4*)&Bs[k][j4] = *(const float4*)&Wx[(size_t)(k0 + k) * DH + bn + j4];
        }
        __syncthreads();

        #pragma unroll
        for (int k = 0; k < 16; ++k) {
            float a0 = As[k][tr * 4 + 0], a1 = As[k][tr * 4 + 1];
            float a2 = As[k][tr * 4 + 2], a3 = As[k][tr * 4 + 3];
            float b0 = Bs[k][tc * 4 + 0], b1 = Bs[k][tc * 4 + 1];
            float b2 = Bs[k][tc * 4 + 2], b3 = Bs[k][tc * 4 + 3];
            acc[0][0] += a0 * b0; acc[0][1] += a0 * b1; acc[0][2] += a0 * b2; acc[0][3] += a0 * b3;
            acc[1][0] += a1 * b0; acc[1][1] += a1 * b1; acc[1][2] += a1 * b2; acc[1][3] += a1 * b3;
            acc[2][0] += a2 * b0; acc[2][1] += a2 * b1; acc[2][2] += a2 * b2; acc[2][3] += a2 * b3;
            acc[3][0] += a3 * b0; acc[3][1] += a3 * b1; acc[3][2] += a3 * b2; acc[3][3] += a3 * b3;
        }
        __syncthreads();
    }

    #pragma unroll
    for (int i = 0; i < 4; ++i) {
        const size_t row = (size_t)(bm + tr * 4 + i);
        #pragma unroll
        for (int j = 0; j < 4; ++j) {
            const int col = bn + tc * 4 + j;
            XW[row * DH + col] = acc[i][j] + b[col];
        }
    }
}

// ---------------- Kernel B: sequential recurrence ---------------------------
// One workgroup (1024 threads) per batch element n. No cross-wg sync needed.
// Thread layout: jgrp = tid & 127 -> output cols [4*jgrp, 4*jgrp+4)
//                ks   = tid >> 7  -> k-slice     [64*ks, 64*ks+64)
__global__ __launch_bounds__(1024) void rnn_rec(
    const float* __restrict__ Wh,   // (512, 512) row-major
    const float* __restrict__ h0,   // (64, 512)
    float* __restrict__ out)        // (64, 512, 512); holds xw on entry
{
    __shared__ float hsh[DH];
    __shared__ float part[8][DH];

    const int n     = blockIdx.x;
    const int tid   = threadIdx.x;
    const int jgrp  = tid & 127;
    const int ks    = tid >> 7;
    const int kbase = ks * 64;

    if (tid < DH) hsh[tid] = h0[(size_t)n * DH + tid];
    __syncthreads();

    const float4* __restrict__ Wh4 = (const float4*)Wh;  // row k = 128 float4
    float* __restrict__ outn = out + (size_t)n * 512 * DH;

    // Preload xw for t=0 (threads 0..511 own column j = tid)
    float xw_cur = (tid < DH) ? outn[tid] : 0.0f;

    for (int t = 0; t < 512; ++t) {
        // Prefetch next step's xw early; latency hides under the k-loop.
        float xw_next = 0.0f;
        if (tid < DH && t < 511) xw_next = outn[(size_t)(t + 1) * DH + tid];

        float4 acc = {0.0f, 0.0f, 0.0f, 0.0f};
        #pragma unroll 8
        for (int k = 0; k < 64; ++k) {
            const float hk = hsh[kbase + k];
            const float4 w = Wh4[(size_t)(kbase + k) * 128 + jgrp];
            acc.x += hk * w.x;
            acc.y += hk * w.y;
            acc.z += hk * w.z;
            acc.w += hk * w.w;
        }
        *(float4*)&part[ks][jgrp * 4] = acc;
        __syncthreads();

        if (tid < DH) {
            const int j = tid;
            float s = part[0][j] + part[1][j] + part[2][j] + part[3][j]
                    + part[4][j] + part[5][j] + part[6][j] + part[7][j];
            const float hv = tanhf(xw_cur + s);
            hsh[j] = hv;
            outn[(size_t)t * DH + j] = hv;
            xw_cur = xw_next;
        }
        __syncthreads();
    }
}

extern "C" void kernel_launch(void* const* d_in, const int* in_sizes, int n_in,
                              void* d_out, int out_size, void* d_ws, size_t ws_size,
                              hipStream_t stream) {
    const float* x  = (const float*)d_in[0];  // (64, 512, 512)
    const float* h0 = (const float*)d_in[1];  // (64, 512)
    const float* Wx = (const float*)d_in[2];  // (512, 512)
    const float* Wh = (const float*)d_in[3];  // (512, 512)
    const float* b  = (const float*)d_in[4];  // (512,)
    float* out = (float*)d_out;               // (64, 512, 512)

    // Kernel A: xw = x @ Wx + b, written into d_out.
    xw_gemm<<<dim3(MTOT / 64, DH / 64), 256, 0, stream>>>(x, Wx, b, out);

    // Kernel B: sequential recurrence, one wg per batch element.
    rnn_rec<<<64, 1024, 0, stream>>>(Wh, h0, out);
}